// Round 9
// baseline (2855.446 us; speedup 1.0000x reference)
//
#include <hip/hip_runtime.h>
#include <hip/hip_bf16.h>
#include <math.h>

#define VOCAB 50257
#define NCLS 20
#define EDIM 64
#define HDIM 64
#define BATCH 128
#define TLEN 2048

typedef float v2f __attribute__((ext_vector_type(2)));

// Static device scratch: no dependence on ws_size, graph-capture safe.
__device__ float g_P[(size_t)2 * VOCAB * 192];   // 77.2 MB, input-projected vocab table (bias folded)
__device__ float g_feats[BATCH * 256];           // pooled features
__device__ float g_probe[2 * BATCH * 64];        // probe sink (never read by outputs)

__device__ __forceinline__ float fast_rcp(float x) { return __builtin_amdgcn_rcpf(x); }

__device__ __forceinline__ float fsigmoid(float x) {
    return fast_rcp(1.f + __expf(-x));
}
__device__ __forceinline__ float ftanh(float x) {
    float e = __expf(2.f * x);
    return 1.f - 2.f * fast_rcp(e + 1.f);
}

// ======================= DIAGNOSTIC PROBES (round 8) =======================
// Eight structural rewrites all land at ~950-1030 cyc/step; the component model is
// wrong by ~2x somewhere. These four single-wave kernels decompose the step:
//   probe_dot        = 96 v2f FMA dot + reduce + bounded linear h update (VALU floor)
//   probe_lds        = + real h LDS round trip (write h, 16 ds_read_b128 broadcasts)
//   probe_fullmath   = + exact sigmoid/tanh gate tail (constant x inputs)
//   probe_gather     = ONLY the token->P asm ring with tied vmcnt + sink FMA
// gru_seq(822us) - probe_fullmath = gather/wait residue; cross-check vs probe_gather.

// shared weight prologue: 16 floats -> 8 named v2f (register-resident at this shape)
#define PROBE_WINIT(SRC)                                                        \
    v2f w0, w1, w2, w3, w4, w5, w6, w7;                                         \
    {                                                                           \
        const float4* p_ = (const float4*)((SRC) + (size_t)lane * 64);          \
        float4 q0 = p_[0]; w0 = (v2f){q0.x, q0.y}; w1 = (v2f){q0.z, q0.w};      \
        float4 q1 = p_[1]; w2 = (v2f){q1.x, q1.y}; w3 = (v2f){q1.z, q1.w};      \
        float4 q2 = p_[2]; w4 = (v2f){q2.x, q2.y}; w5 = (v2f){q2.z, q2.w};      \
        float4 q3 = p_[3]; w6 = (v2f){q3.x, q3.y}; w7 = (v2f){q3.z, q3.w};      \
    }

// 6 accumulators x 16 FMAs = 96 v2f FMAs per step, mimicking the real dot exactly
#define PROBE_DOT6(H01, H23)                                                    \
        ar0 = __builtin_elementwise_fma(H01, w0, ar0);                          \
        az0 = __builtin_elementwise_fma(H01, w2, az0);                          \
        an0 = __builtin_elementwise_fma(H01, w4, an0);                          \
        ar1 = __builtin_elementwise_fma(H23, w1, ar1);                          \
        az1 = __builtin_elementwise_fma(H23, w3, az1);                          \
        an1 = __builtin_elementwise_fma(H23, w5, an1);

__global__ __launch_bounds__(64, 1) void probe_dot(const float* __restrict__ whh) {
    const int lane = threadIdx.x;
    PROBE_WINIT(whh)
    float h = 0.001f * lane, sum = 0.f, mx = -INFINITY;
#pragma unroll 4
    for (int s = 0; s < TLEN; s++) {
        v2f hv = {h, h};
        v2f ar0 = {0,0}, ar1 = {0,0}, az0 = {0,0}, az1 = {0,0}, an0 = {0,0}, an1 = {0,0};
#pragma unroll
        for (int k = 0; k < 16; k++) { PROBE_DOT6(hv, hv) }
        float hr = (ar0.x + ar0.y) + (ar1.x + ar1.y);
        float hz = (az0.x + az0.y) + (az1.x + az1.y);
        float hn = (an0.x + an0.y) + (an1.x + an1.y);
        h = fmaf(hr + hz + hn, 1e-6f, 1e-3f);      // bounded, keeps dependency
        sum += h; mx = fmaxf(mx, h);
    }
    g_probe[blockIdx.x * 64 + lane] = sum + mx + h;
}

__global__ __launch_bounds__(64, 1) void probe_lds(const float* __restrict__ whh) {
    const int lane = threadIdx.x;
    PROBE_WINIT(whh)
    __shared__ __align__(16) float h_lds[64];
    float h = 0.001f * lane, sum = 0.f, mx = -INFINITY;
    h_lds[lane] = h;
#pragma unroll 4
    for (int s = 0; s < TLEN; s++) {
        v2f ar0 = {0,0}, ar1 = {0,0}, az0 = {0,0}, az1 = {0,0}, an0 = {0,0}, an1 = {0,0};
#pragma unroll
        for (int k = 0; k < 8; k++) {              // 16 b128 broadcast reads (2 per k)
            float4 ha = *(const float4*)(h_lds + 8 * k);
            float4 hb = *(const float4*)(h_lds + 8 * k + 4);
            v2f a01 = {ha.x, ha.y}, a23 = {ha.z, ha.w};
            v2f b01 = {hb.x, hb.y}, b23 = {hb.z, hb.w};
            PROBE_DOT6(a01, a23)
            ar0 = __builtin_elementwise_fma(b01, w6, ar0);
            az0 = __builtin_elementwise_fma(b01, w0, az0);
            an0 = __builtin_elementwise_fma(b01, w2, an0);
            ar1 = __builtin_elementwise_fma(b23, w7, ar1);
            az1 = __builtin_elementwise_fma(b23, w1, az1);
            an1 = __builtin_elementwise_fma(b23, w3, an1);
        }
        float hr = (ar0.x + ar0.y) + (ar1.x + ar1.y);
        float hz = (az0.x + az0.y) + (az1.x + az1.y);
        float hn = (an0.x + an0.y) + (an1.x + an1.y);
        h = fmaf(hr + hz + hn, 1e-6f, 1e-3f);
        sum += h; mx = fmaxf(mx, h);
        h_lds[lane] = h;                           // single wave: in-order LDS, no barrier
    }
    g_probe[blockIdx.x * 64 + lane] = sum + mx + h;
}

__global__ __launch_bounds__(64, 1) void probe_fullmath(const float* __restrict__ whh,
                                                        const float* __restrict__ bhh) {
    const int lane = threadIdx.x;
    PROBE_WINIT(whh)
    const float br = bhh[lane], bz = bhh[64 + lane], bn = bhh[128 + lane];
    __shared__ __align__(16) float h_lds[64];
    float h = 0.f, sum = 0.f, mx = -INFINITY;
    h_lds[lane] = h;
#pragma unroll 4
    for (int s = 0; s < TLEN; s++) {
        v2f ar0 = {0,0}, ar1 = {0,0}, az0 = {0,0}, az1 = {0,0}, an0 = {0,0}, an1 = {0,0};
#pragma unroll
        for (int k = 0; k < 8; k++) {
            float4 ha = *(const float4*)(h_lds + 8 * k);
            float4 hb = *(const float4*)(h_lds + 8 * k + 4);
            v2f a01 = {ha.x, ha.y}, a23 = {ha.z, ha.w};
            v2f b01 = {hb.x, hb.y}, b23 = {hb.z, hb.w};
            PROBE_DOT6(a01, a23)
            ar0 = __builtin_elementwise_fma(b01, w6, ar0);
            az0 = __builtin_elementwise_fma(b01, w0, az0);
            an0 = __builtin_elementwise_fma(b01, w2, an0);
            ar1 = __builtin_elementwise_fma(b23, w7, ar1);
            az1 = __builtin_elementwise_fma(b23, w1, az1);
            an1 = __builtin_elementwise_fma(b23, w3, an1);
        }
        float hr = (ar0.x + ar0.y) + (ar1.x + ar1.y);
        float hz = (az0.x + az0.y) + (az1.x + az1.y);
        float hn = (an0.x + an0.y) + (an1.x + an1.y);
        float r = fsigmoid(0.1f + hr + br);        // exact gate tail, constant x inputs
        float z = fsigmoid(-0.2f + hz + bz);
        float n = ftanh(0.3f + r * (hn + bn));
        h = fmaf(z, h - n, n);
        sum += h; mx = fmaxf(mx, h);
        h_lds[lane] = h;
    }
    g_probe[blockIdx.x * 64 + lane] = sum + mx + h;
}

__global__ __launch_bounds__(64, 1) void probe_gather(const int* __restrict__ tokens) {
    const int lane = threadIdx.x;
    const int blk = blockIdx.x;
    const int b = blk >> 1;
    const int dir = blk & 1;
    const float* Pd = g_P + (size_t)dir * VOCAB * 192;
    __shared__ __align__(16) int tok_lds[TLEN];
    {
        const int4* src = (const int4*)(tokens + (size_t)b * TLEN);
        int4* dst = (int4*)tok_lds;
        for (int t = lane; t < TLEN / 4; t += 64) dst[t] = src[t];
    }
    auto tok_at = [&](int s) -> int {
        int ss = s < TLEN ? s : TLEN - 1;
        return tok_lds[dir ? (TLEN - 1 - ss) : ss];
    };
    float acc = 0.f;
    float xr0, xz0, xn0, xr1, xz1, xn1, xr2, xz2, xn2, xr3, xz3, xn3;
#define PG_PRE(SL, D) do {                                                             \
        const float* rd_ = Pd + (size_t)tok_at(D) * 192;                               \
        asm volatile("global_load_dword %0, %1, off" : "=v"(xr##SL) : "v"(rd_ + lane));       \
        asm volatile("global_load_dword %0, %1, off" : "=v"(xz##SL) : "v"(rd_ + 64 + lane));  \
        asm volatile("global_load_dword %0, %1, off" : "=v"(xn##SL) : "v"(rd_ + 128 + lane)); \
    } while (0)
    PG_PRE(0, 0); PG_PRE(1, 1); PG_PRE(2, 2); PG_PRE(3, 3);
#define PG_STEP(SL, SB) do {                                                           \
        const int tN_ = tok_at((SB) + 4);                                              \
        asm volatile("s_waitcnt vmcnt(9)" : "+v"(xr##SL), "+v"(xz##SL), "+v"(xn##SL)); \
        acc = fmaf(xr##SL, 1e-7f, acc);                                                \
        acc = fmaf(xz##SL, 1e-7f, acc);                                                \
        acc = fmaf(xn##SL, 1e-7f, acc);                                                \
        const float* rp_ = Pd + (size_t)tN_ * 192;                                     \
        asm volatile("global_load_dword %0, %1, off" : "=v"(xr##SL) : "v"(rp_ + lane));       \
        asm volatile("global_load_dword %0, %1, off" : "=v"(xz##SL) : "v"(rp_ + 64 + lane));  \
        asm volatile("global_load_dword %0, %1, off" : "=v"(xn##SL) : "v"(rp_ + 128 + lane)); \
    } while (0)
    for (int s = 0; s < TLEN; s += 4) {
        PG_STEP(0, s + 0); PG_STEP(1, s + 1); PG_STEP(2, s + 2); PG_STEP(3, s + 3);
    }
    asm volatile("s_waitcnt vmcnt(0)" ::: "memory");
    g_probe[blockIdx.x * 64 + lane] = acc;
#undef PG_PRE
#undef PG_STEP
}

// ===================== REAL PIPELINE (round-4 verbatim, best: gru 822us) =====================

__global__ __launch_bounds__(384) void precompute_P(
    const float* __restrict__ emb,
    const float* __restrict__ wih_f, const float* __restrict__ bih_f,
    const float* __restrict__ wih_b, const float* __restrict__ bih_b)
{
    const int t = threadIdx.x;
    const int dir = t / 192;
    const int g = t % 192;
    const float* wih = dir ? wih_b : wih_f;
    const float* bih = dir ? bih_b : bih_f;

    float w[64];
#pragma unroll
    for (int e = 0; e < 64; e += 4) {
        float4 v = *(const float4*)(wih + (size_t)g * 64 + e);
        w[e] = v.x; w[e + 1] = v.y; w[e + 2] = v.z; w[e + 3] = v.w;
    }
    const float bias = bih[g];
    float* Pd = g_P + (size_t)dir * VOCAB * 192;

    for (int v = blockIdx.x * 2; v < VOCAB; v += gridDim.x * 2) {
        const int v1ok = (v + 1 < VOCAB);
        const float4* e0 = (const float4*)(emb + (size_t)v * 64);
        const float4* e1 = (const float4*)(emb + (size_t)(v1ok ? v + 1 : v) * 64);
        float a0 = bias, a1 = bias;
#pragma unroll
        for (int e4 = 0; e4 < 16; e4++) {
            float4 x = e0[e4];
            float4 y = e1[e4];
            a0 = fmaf(x.x, w[4 * e4 + 0], a0);
            a1 = fmaf(y.x, w[4 * e4 + 0], a1);
            a0 = fmaf(x.y, w[4 * e4 + 1], a0);
            a1 = fmaf(y.y, w[4 * e4 + 1], a1);
            a0 = fmaf(x.z, w[4 * e4 + 2], a0);
            a1 = fmaf(y.z, w[4 * e4 + 2], a1);
            a0 = fmaf(x.w, w[4 * e4 + 3], a0);
            a1 = fmaf(y.w, w[4 * e4 + 3], a1);
        }
        Pd[(size_t)v * 192 + g] = a0;
        if (v1ok) Pd[(size_t)(v + 1) * 192 + g] = a1;
    }
}

__global__ __launch_bounds__(64, 1) __attribute__((amdgpu_waves_per_eu(1, 1)))
void gru_seq(
    const int* __restrict__ tokens,
    const float* __restrict__ whh_f, const float* __restrict__ bhh_f,
    const float* __restrict__ whh_b, const float* __restrict__ bhh_b)
{
    const int lane = threadIdx.x;
    const int blk = blockIdx.x;
    const int b = blk >> 1;
    const int dir = blk & 1;
    const float* whh = dir ? whh_b : whh_f;
    const float* bhh = dir ? bhh_b : bhh_f;
    const float* Pd = g_P + (size_t)dir * VOCAB * 192;

    __shared__ __align__(16) float h_lds[64];
    __shared__ __align__(16) int tok_lds[TLEN];

    {
        const int4* src = (const int4*)(tokens + (size_t)b * TLEN);
        int4* dst = (int4*)tok_lds;
        for (int t = lane; t < TLEN / 4; t += 64) dst[t] = src[t];
    }

    v2f wr[32], wz[32], wn[32];
    {
        const float* pr = whh + (size_t)(0 + lane) * 64;
        const float* pz = whh + (size_t)(64 + lane) * 64;
        const float* pn = whh + (size_t)(128 + lane) * 64;
#pragma unroll
        for (int k = 0; k < 16; k++) {
            float4 a = *(const float4*)(pr + 4 * k);
            wr[2 * k] = (v2f){a.x, a.y}; wr[2 * k + 1] = (v2f){a.z, a.w};
            float4 c = *(const float4*)(pz + 4 * k);
            wz[2 * k] = (v2f){c.x, c.y}; wz[2 * k + 1] = (v2f){c.z, c.w};
            float4 d = *(const float4*)(pn + 4 * k);
            wn[2 * k] = (v2f){d.x, d.y}; wn[2 * k + 1] = (v2f){d.z, d.w};
        }
    }
    const float br = bhh[lane], bz = bhh[64 + lane], bn = bhh[128 + lane];

    h_lds[lane] = 0.f;
    float h = 0.f, sum = 0.f, mx = -INFINITY;

    auto tok_at = [&](int s) -> int {
        int ss = s < TLEN ? s : TLEN - 1;
        return tok_lds[dir ? (TLEN - 1 - ss) : ss];
    };

    float x0, x1, x2, x3;  (void)x0; (void)x1; (void)x2; (void)x3;
    float xr0, xz0, xn0, xr1, xz1, xn1, xr2, xz2, xn2, xr3, xz3, xn3;

#define GRU_PRE(SL, D) do {                                                        \
        const float* rd_ = Pd + (size_t)tok_at(D) * 192;                           \
        asm volatile("global_load_dword %0, %1, off" : "=v"(xr##SL) : "v"(rd_ + lane));       \
        asm volatile("global_load_dword %0, %1, off" : "=v"(xz##SL) : "v"(rd_ + 64 + lane));  \
        asm volatile("global_load_dword %0, %1, off" : "=v"(xn##SL) : "v"(rd_ + 128 + lane)); \
    } while (0)

    GRU_PRE(0, 0); GRU_PRE(1, 1); GRU_PRE(2, 2); GRU_PRE(3, 3);

#define GRU_STEP(SL, SB) do {                                                      \
        const int tN_ = tok_at((SB) + 4);                                          \
        v2f ar0 = {0.f, 0.f}, ar1 = {0.f, 0.f};                                    \
        v2f az0 = {0.f, 0.f}, az1 = {0.f, 0.f};                                    \
        v2f an0 = {0.f, 0.f}, an1 = {0.f, 0.f};                                    \
        _Pragma("unroll")                                                          \
        for (int k = 0; k < 16; k++) {                                             \
            float4 h4 = *(const float4*)(h_lds + 4 * k);                           \
            v2f h01 = {h4.x, h4.y}, h23 = {h4.z, h4.w};                            \
            ar0 = __builtin_elementwise_fma(h01, wr[2 * k], ar0);                  \
            az0 = __builtin_elementwise_fma(h01, wz[2 * k], az0);                  \
            an0 = __builtin_elementwise_fma(h01, wn[2 * k], an0);                  \
            ar1 = __builtin_elementwise_fma(h23, wr[2 * k + 1], ar1);              \
            az1 = __builtin_elementwise_fma(h23, wz[2 * k + 1], az1);              \
            an1 = __builtin_elementwise_fma(h23, wn[2 * k + 1], an1);              \
        }                                                                          \
        float hr = (ar0.x + ar0.y) + (ar1.x + ar1.y);                              \
        float hz = (az0.x + az0.y) + (az1.x + az1.y);                              \
        float hn = (an0.x + an0.y) + (an1.x + an1.y);                              \
        asm volatile("s_waitcnt vmcnt(9)"                                          \
                     : "+v"(xr##SL), "+v"(xz##SL), "+v"(xn##SL));                  \
        float r_ = fsigmoid(xr##SL + hr + br);                                     \
        float z_ = fsigmoid(xz##SL + hz + bz);                                     \
        float n_ = ftanh(xn##SL + r_ * (hn + bn));                                 \
        h = fmaf(z_, h - n_, n_);                                                  \
        sum += h;                                                                  \
        mx = fmaxf(mx, h);                                                         \
        h_lds[lane] = h;                                                           \
        const float* rp_ = Pd + (size_t)tN_ * 192;                                 \
        asm volatile("global_load_dword %0, %1, off" : "=v"(xr##SL) : "v"(rp_ + lane));       \
        asm volatile("global_load_dword %0, %1, off" : "=v"(xz##SL) : "v"(rp_ + 64 + lane));  \
        asm volatile("global_load_dword %0, %1, off" : "=v"(xn##SL) : "v"(rp_ + 128 + lane)); \
    } while (0)

    for (int s = 0; s < TLEN; s += 4) {
        GRU_STEP(0, s + 0);
        GRU_STEP(1, s + 1);
        GRU_STEP(2, s + 2);
        GRU_STEP(3, s + 3);
    }
    asm volatile("s_waitcnt vmcnt(0)" ::: "memory");

    g_feats[b * 256 + dir * 64 + lane] = sum * (1.f / TLEN);
    g_feats[b * 256 + 128 + dir * 64 + lane] = mx;
#undef GRU_PRE
#undef GRU_STEP
}

__global__ __launch_bounds__(64) void classifier(
    const float* __restrict__ w1, const float* __restrict__ b1,
    const float* __restrict__ w2, const float* __restrict__ b2,
    float* __restrict__ out)
{
    const int b = blockIdx.x;
    const int i = threadIdx.x;
    __shared__ float f[256];
    __shared__ float hid[64];
    for (int c = i; c < 256; c += 64) f[c] = g_feats[b * 256 + c];
    __syncthreads();

    float acc = b1[i];
    const float* wrow = w1 + (size_t)i * 256;
#pragma unroll 16
    for (int c = 0; c < 256; c++) acc = fmaf(f[c], wrow[c], acc);
    hid[i] = acc * 0.5f * (1.f + erff(acc * 0.70710678118654752f));
    __syncthreads();

    if (i < NCLS) {
        float o = b2[i];
        const float* w2r = w2 + (size_t)i * 64;
#pragma unroll
        for (int j = 0; j < 64; j++) o = fmaf(hid[j], w2r[j], o);
        out[b * NCLS + i] = o;
    }
}

extern "C" void kernel_launch(void* const* d_in, const int* in_sizes, int n_in,
                              void* d_out, int out_size, void* d_ws, size_t ws_size,
                              hipStream_t stream) {
    const int*   tokens = (const int*)  d_in[0];
    const float* emb    = (const float*)d_in[1];
    const float* wih_f  = (const float*)d_in[2];
    const float* whh_f  = (const float*)d_in[3];
    const float* bih_f  = (const float*)d_in[4];
    const float* bhh_f  = (const float*)d_in[5];
    const float* wih_b  = (const float*)d_in[6];
    const float* whh_b  = (const float*)d_in[7];
    const float* bih_b  = (const float*)d_in[8];
    const float* bhh_b  = (const float*)d_in[9];
    const float* w1     = (const float*)d_in[10];
    const float* b1     = (const float*)d_in[11];
    const float* w2     = (const float*)d_in[12];
    const float* b2     = (const float*)d_in[13];
    float* out = (float*)d_out;

    // diagnostics first (write only g_probe; durations land in the rocprof table)
    probe_dot<<<256, 64, 0, stream>>>(whh_f);
    probe_lds<<<256, 64, 0, stream>>>(whh_f);
    probe_fullmath<<<256, 64, 0, stream>>>(whh_f, bhh_f);

    // real pipeline (round-4 verbatim)
    precompute_P<<<4096, 384, 0, stream>>>(emb, wih_f, bih_f, wih_b, bih_b);
    probe_gather<<<256, 64, 0, stream>>>(tokens);   // after P is filled, faithful addresses
    gru_seq<<<2 * BATCH, 64, 0, stream>>>(tokens, whh_f, bhh_f, whh_b, bhh_b);
    classifier<<<BATCH, 64, 0, stream>>>(w1, b1, w2, b2, out);
}